// Round 1
// baseline (402.056 us; speedup 1.0000x reference)
//
#include <hip/hip_runtime.h>
#include <math.h>

// Problem constants: B=1, C=64, H=W=64, N=4096, heads=8, dh=8, inner=64,
// hid_lc=32, hid_f=256. All fp32.
#define NPIX 4096
#define IMG 64

// ---------------------------------------------------------------------------
// lc1: h1[32][4096] = relu(conv3x3(luma, lc1_w) + b), 1 input channel, pad=1
__global__ __launch_bounds__(256) void lc1_kernel(
    const float* __restrict__ luma, const float* __restrict__ w,
    const float* __restrict__ b, float* __restrict__ h1) {
  int p = blockIdx.x * 256 + threadIdx.x;
  int py = p >> 6, px = p & 63;
  float v[9];
#pragma unroll
  for (int dy = 0; dy < 3; dy++)
#pragma unroll
    for (int dx = 0; dx < 3; dx++) {
      int y = py + dy - 1, x = px + dx - 1;
      v[dy * 3 + dx] =
          (y >= 0 && y < IMG && x >= 0 && x < IMG) ? luma[y * IMG + x] : 0.f;
    }
  for (int oc = 0; oc < 32; oc++) {
    float s = b[oc];
#pragma unroll
    for (int t = 0; t < 9; t++) s = fmaf(w[oc * 9 + t], v[t], s);
    h1[oc * NPIX + p] = fmaxf(s, 0.f);
  }
}

// ---------------------------------------------------------------------------
// invL: pooled = avgpool3x3(1-luma) (count_include_pad -> /9), then center.
__global__ __launch_bounds__(512) void invl_kernel(
    const float* __restrict__ luma, float* __restrict__ invl) {
  __shared__ float red[512];
  float vals[8];
  float loc = 0.f;
#pragma unroll
  for (int r = 0; r < 8; r++) {
    int p = r * 512 + threadIdx.x;
    int py = p >> 6, px = p & 63;
    float s = 0.f;
#pragma unroll
    for (int dy = 0; dy < 3; dy++)
#pragma unroll
      for (int dx = 0; dx < 3; dx++) {
        int y = py + dy - 1, x = px + dx - 1;
        if (y >= 0 && y < IMG && x >= 0 && x < IMG)
          s += 1.f - luma[y * IMG + x];
      }
    s *= (1.f / 9.f);
    vals[r] = s;
    loc += s;
  }
  red[threadIdx.x] = loc;
  __syncthreads();
  for (int st = 256; st > 0; st >>= 1) {
    if (threadIdx.x < st) red[threadIdx.x] += red[threadIdx.x + st];
    __syncthreads();
  }
  float mean = red[0] * (1.f / 4096.f);
#pragma unroll
  for (int r = 0; r < 8; r++) invl[r * 512 + threadIdx.x] = vals[r] - mean;
}

// ---------------------------------------------------------------------------
// lc2: h2[32][4096] = relu(conv3x3(h1, lc2_w[32][32][3][3]) + b), pad=1.
// grid: (16 tiles of 16x16, 8 oc-groups of 4)
__global__ __launch_bounds__(256) void lc2_kernel(
    const float* __restrict__ h1, const float* __restrict__ w,
    const float* __restrict__ b, float* __restrict__ h2) {
  __shared__ float tin[32][324];   // 18x18 halo per ic
  __shared__ float sw[4][32][9];
  int tile = blockIdx.x, ocg = blockIdx.y;
  int ty0 = (tile >> 2) * 16, tx0 = (tile & 3) * 16;
  for (int idx = threadIdx.x; idx < 32 * 324; idx += 256) {
    int ic = idx / 324, pos = idx % 324;
    int py = pos / 18, px = pos % 18;
    int gy = ty0 + py - 1, gx = tx0 + px - 1;
    tin[ic][pos] = (gy >= 0 && gy < IMG && gx >= 0 && gx < IMG)
                       ? h1[ic * NPIX + gy * IMG + gx]
                       : 0.f;
  }
  for (int idx = threadIdx.x; idx < 4 * 32 * 9; idx += 256) {
    int o = idx / 288, r = idx % 288;
    sw[o][r / 9][r % 9] = w[(ocg * 4 + o) * 288 + r];
  }
  __syncthreads();
  int ly = threadIdx.x >> 4, lx = threadIdx.x & 15;
  int p = (ty0 + ly) * IMG + tx0 + lx;
  float acc[4];
#pragma unroll
  for (int o = 0; o < 4; o++) acc[o] = b[ocg * 4 + o];
  for (int ic = 0; ic < 32; ic++) {
    float v[9];
#pragma unroll
    for (int dy = 0; dy < 3; dy++)
#pragma unroll
      for (int dx = 0; dx < 3; dx++)
        v[dy * 3 + dx] = tin[ic][(ly + dy) * 18 + lx + dx];
#pragma unroll
    for (int o = 0; o < 4; o++)
#pragma unroll
      for (int t = 0; t < 9; t++) acc[o] = fmaf(sw[o][ic][t], v[t], acc[o]);
  }
#pragma unroll
  for (int o = 0; o < 4; o++)
    h2[(ocg * 4 + o) * NPIX + p] = fmaxf(acc[o], 0.f);
}

// ---------------------------------------------------------------------------
// Per-pixel LayerNorm over 64 channels (two-pass, exact).
__global__ __launch_bounds__(256) void ln_kernel(
    const float* __restrict__ x, const float* __restrict__ w,
    const float* __restrict__ b, float* __restrict__ y) {
  int p = blockIdx.x * 256 + threadIdx.x;
  float s = 0.f;
  for (int c = 0; c < 64; c++) s += x[c * NPIX + p];
  float mu = s * (1.f / 64.f);
  float var = 0.f;
  for (int c = 0; c < 64; c++) {
    float d = x[c * NPIX + p] - mu;
    var = fmaf(d, d, var);
  }
  float rs = rsqrtf(var * (1.f / 64.f) + 1e-5f);
  for (int c = 0; c < 64; c++)
    y[c * NPIX + p] = (x[c * NPIX + p] - mu) * rs * w[c] + b[c];
}

// ---------------------------------------------------------------------------
// Generic SGEMM: C[M][4096] = W[M][K] * X[K][4096] + bias (+resid)
// grid: (4096/64, M/64); block 256; per-thread 4x4.
__global__ __launch_bounds__(256) void gemm_kernel(
    const float* __restrict__ W, const float* __restrict__ X,
    const float* __restrict__ bias, const float* __restrict__ resid,
    float* __restrict__ C, int K) {
  __shared__ float ws[16][64];
  __shared__ float xs[16][64];
  int n0 = blockIdx.x * 64, m0 = blockIdx.y * 64;
  int tx = threadIdx.x & 15, ty = threadIdx.x >> 4;
  float acc[4][4] = {};
  for (int k0 = 0; k0 < K; k0 += 16) {
    for (int idx = threadIdx.x; idx < 1024; idx += 256) {
      int m = idx & 63, k = idx >> 6;
      ws[k][m] = W[(m0 + m) * K + k0 + k];  // W tiny & cache-hot
    }
    for (int idx = threadIdx.x; idx < 1024; idx += 256) {
      int k = idx >> 6, n = idx & 63;
      xs[k][n] = X[(k0 + k) * NPIX + n0 + n];
    }
    __syncthreads();
#pragma unroll
    for (int kk = 0; kk < 16; kk++) {
      const float4 a = *(const float4*)&ws[kk][ty * 4];
      const float4 bb = *(const float4*)&xs[kk][tx * 4];
      float av[4] = {a.x, a.y, a.z, a.w};
      float bv[4] = {bb.x, bb.y, bb.z, bb.w};
#pragma unroll
      for (int im = 0; im < 4; im++)
#pragma unroll
        for (int in = 0; in < 4; in++)
          acc[im][in] = fmaf(av[im], bv[in], acc[im][in]);
    }
    __syncthreads();
  }
#pragma unroll
  for (int im = 0; im < 4; im++) {
    int m = m0 + ty * 4 + im;
    float bv = bias[m];
#pragma unroll
    for (int in = 0; in < 4; in++) {
      int n = n0 + tx * 4 + in;
      float v = acc[im][in] + bv;
      if (resid) v += resid[m * NPIX + n];
      C[m * NPIX + n] = v;
    }
  }
}

// ---------------------------------------------------------------------------
// Modulate qkv with (g, bt), add alpha*invL to q, repack to [h][n][d].
__global__ __launch_bounds__(256) void qkvmod_kernel(
    const float* __restrict__ qkv, const float* __restrict__ g,
    const float* __restrict__ bt, const float* __restrict__ invl,
    const float* __restrict__ alpha, float* __restrict__ q,
    float* __restrict__ k, float* __restrict__ v) {
  int t = blockIdx.x * 256 + threadIdx.x;  // 0..32767 = h*4096+n
  int n = t & 4095, h = t >> 12;
  float iv = alpha[0] * invl[n];
  float* dsts[3] = {q, k, v};
#pragma unroll
  for (int part = 0; part < 3; part++) {
    float out[8];
#pragma unroll
    for (int d = 0; d < 8; d++) {
      int c = h * 8 + d;
      float r = fmaf(g[c * NPIX + n], qkv[(part * 64 + c) * NPIX + n],
                     bt[c * NPIX + n]);
      if (part == 0) r += iv;
      out[d] = r;
    }
    float4* dp = (float4*)&dsts[part][(size_t)(h * NPIX + n) * 8];
    dp[0] = make_float4(out[0], out[1], out[2], out[3]);
    dp[1] = make_float4(out[4], out[5], out[6], out[7]);
  }
}

// ---------------------------------------------------------------------------
// Flash-decode attention partials. grid (16 iblocks, 8 heads, 4 jparts).
// Each thread owns one query row; online softmax over its 1024-j slice.
#define TJ 512
__global__ __launch_bounds__(256) void attn_kernel(
    const float* __restrict__ q, const float* __restrict__ k,
    const float* __restrict__ v, float* __restrict__ pacc,
    float* __restrict__ pml) {
  __shared__ float ks[TJ][8];
  __shared__ float vs[TJ][8];
  int tid = threadIdx.x;
  int i = blockIdx.x * 256 + tid;
  int h = blockIdx.y;
  int jp = blockIdx.z;
  const float* qp = q + (size_t)(h * NPIX + i) * 8;
  float4 q0 = ((const float4*)qp)[0], q1 = ((const float4*)qp)[1];
  float qr[8] = {q0.x, q0.y, q0.z, q0.w, q1.x, q1.y, q1.z, q1.w};
  float m = -INFINITY, l = 0.f, acc[8] = {};
  const float scale = 0.35355339059327376f;  // 8^-0.5
  for (int jt = 0; jt < 2; jt++) {
    int j0 = jp * 1024 + jt * TJ;
    const float4* kg = (const float4*)(k + (size_t)(h * NPIX + j0) * 8);
    const float4* vg = (const float4*)(v + (size_t)(h * NPIX + j0) * 8);
    float4* ksv = (float4*)ks;
    float4* vsv = (float4*)vs;
    for (int idx = tid; idx < TJ * 2; idx += 256) {
      ksv[idx] = kg[idx];
      vsv[idx] = vg[idx];
    }
    __syncthreads();
    for (int j = 0; j < TJ; j++) {
      float s = (fmaf(qr[0], ks[j][0], qr[1] * ks[j][1]) +
                 fmaf(qr[2], ks[j][2], qr[3] * ks[j][3])) +
                (fmaf(qr[4], ks[j][4], qr[5] * ks[j][5]) +
                 fmaf(qr[6], ks[j][6], qr[7] * ks[j][7]));
      s *= scale;
      float mn = fmaxf(m, s);
      float pj = __expf(s - mn);
      float corr = __expf(m - mn);
      l = fmaf(l, corr, pj);
#pragma unroll
      for (int d = 0; d < 8; d++)
        acc[d] = fmaf(acc[d], corr, pj * vs[j][d]);
      m = mn;
    }
    __syncthreads();
  }
  size_t base = (size_t)((jp * 8 + h) * NPIX + i);
  float4* pa = (float4*)&pacc[base * 8];
  pa[0] = make_float4(acc[0], acc[1], acc[2], acc[3]);
  pa[1] = make_float4(acc[4], acc[5], acc[6], acc[7]);
  pml[base * 2] = m;
  pml[base * 2 + 1] = l;
}

// Combine the 4 j-partitions; write attno[c=h*8+d][n].
__global__ __launch_bounds__(256) void attn_combine_kernel(
    const float* __restrict__ pacc, const float* __restrict__ pml,
    float* __restrict__ attno) {
  int t = blockIdx.x * 256 + threadIdx.x;  // h*4096+n
  int n = t & 4095, h = t >> 12;
  float M = -INFINITY;
#pragma unroll
  for (int p = 0; p < 4; p++)
    M = fmaxf(M, pml[(size_t)((p * 8 + h) * NPIX + n) * 2]);
  float L = 0.f, o[8] = {};
#pragma unroll
  for (int p = 0; p < 4; p++) {
    size_t base = (size_t)((p * 8 + h) * NPIX + n);
    float mm = pml[base * 2], ll = pml[base * 2 + 1];
    float c = __expf(mm - M);
    L = fmaf(ll, c, L);
#pragma unroll
    for (int d = 0; d < 8; d++) o[d] = fmaf(pacc[base * 8 + d], c, o[d]);
  }
  float inv = 1.f / L;
#pragma unroll
  for (int d = 0; d < 8; d++)
    attno[(h * 8 + d) * NPIX + n] = o[d] * inv;
}

// ---------------------------------------------------------------------------
// Depthwise 3x3 (pad=1, groups=256) + exact GELU.
__global__ __launch_bounds__(256) void dw_gelu_kernel(
    const float* __restrict__ f1, const float* __restrict__ w,
    const float* __restrict__ b, float* __restrict__ f2) {
  int t = blockIdx.x * 256 + threadIdx.x;  // c*4096+p
  int c = t >> 12, p = t & 4095;
  int py = p >> 6, px = p & 63;
  float s = b[c];
#pragma unroll
  for (int dy = 0; dy < 3; dy++)
#pragma unroll
    for (int dx = 0; dx < 3; dx++) {
      int y = py + dy - 1, x = px + dx - 1;
      if (y >= 0 && y < IMG && x >= 0 && x < IMG)
        s = fmaf(w[c * 9 + dy * 3 + dx], f1[c * NPIX + y * IMG + x], s);
    }
  f2[t] = 0.5f * s * (1.f + erff(s * 0.70710678118654752f));
}

// ---------------------------------------------------------------------------
extern "C" void kernel_launch(void* const* d_in, const int* in_sizes, int n_in,
                              void* d_out, int out_size, void* d_ws,
                              size_t ws_size, hipStream_t stream) {
  const float* x      = (const float*)d_in[0];
  const float* luma   = (const float*)d_in[1];
  const float* ln1_w  = (const float*)d_in[2];
  const float* ln1_b  = (const float*)d_in[3];
  const float* qkv_w  = (const float*)d_in[4];
  const float* qkv_b  = (const float*)d_in[5];
  const float* proj_w = (const float*)d_in[6];
  const float* proj_b = (const float*)d_in[7];
  const float* lc1_w  = (const float*)d_in[8];
  const float* lc1_b  = (const float*)d_in[9];
  const float* lc2_w  = (const float*)d_in[10];
  const float* lc2_b  = (const float*)d_in[11];
  const float* gam_w  = (const float*)d_in[12];
  const float* gam_b  = (const float*)d_in[13];
  const float* bet_w  = (const float*)d_in[14];
  const float* bet_b  = (const float*)d_in[15];
  const float* alpha  = (const float*)d_in[16];
  const float* ln2_w  = (const float*)d_in[17];
  const float* ln2_b  = (const float*)d_in[18];
  const float* ffn1_w = (const float*)d_in[19];
  const float* ffn1_b = (const float*)d_in[20];
  const float* dw_w   = (const float*)d_in[21];
  const float* dw_b   = (const float*)d_in[22];
  const float* ffn2_w = (const float*)d_in[23];
  const float* ffn2_b = (const float*)d_in[24];
  float* out = (float*)d_out;

  float* w = (float*)d_ws;
  float* h1    = w + 0;         // 32*4096
  float* h2    = w + 131072;    // 32*4096
  float* g     = w + 262144;    // 64*4096
  float* bt    = w + 524288;    // 64*4096
  float* invl  = w + 786432;    // 4096
  float* xn    = w + 790528;    // 64*4096
  float* qkv   = w + 1052672;   // 192*4096
  float* qb    = w + 1839104;   // 8*4096*8
  float* kb    = w + 2101248;
  float* vb    = w + 2363392;
  float* attno = w + 2625536;   // 64*4096
  float* x1    = w + 2887680;   // 64*4096
  float* f1    = w + 3149824;   // 256*4096
  float* f2    = w + 4198400;   // 256*4096
  float* pacc  = f1;            // alias: dead before f1 written
  float* pml   = f2;            // alias: dead before f2 written

  // luma conditioning branch
  lc1_kernel<<<16, 256, 0, stream>>>(luma, lc1_w, lc1_b, h1);
  invl_kernel<<<1, 512, 0, stream>>>(luma, invl);
  lc2_kernel<<<dim3(16, 8), 256, 0, stream>>>(h1, lc2_w, lc2_b, h2);
  gemm_kernel<<<dim3(64, 1), 256, 0, stream>>>(gam_w, h2, gam_b, nullptr, g, 32);
  gemm_kernel<<<dim3(64, 1), 256, 0, stream>>>(bet_w, h2, bet_b, nullptr, bt, 32);
  // attention branch
  ln_kernel<<<16, 256, 0, stream>>>(x, ln1_w, ln1_b, xn);
  gemm_kernel<<<dim3(64, 3), 256, 0, stream>>>(qkv_w, xn, qkv_b, nullptr, qkv, 64);
  qkvmod_kernel<<<128, 256, 0, stream>>>(qkv, g, bt, invl, alpha, qb, kb, vb);
  attn_kernel<<<dim3(16, 8, 4), 256, 0, stream>>>(qb, kb, vb, pacc, pml);
  attn_combine_kernel<<<128, 256, 0, stream>>>(pacc, pml, attno);
  gemm_kernel<<<dim3(64, 1), 256, 0, stream>>>(proj_w, attno, proj_b, x, x1, 64);
  // FFN branch
  ln_kernel<<<16, 256, 0, stream>>>(x1, ln2_w, ln2_b, xn);
  gemm_kernel<<<dim3(64, 4), 256, 0, stream>>>(ffn1_w, xn, ffn1_b, nullptr, f1, 64);
  dw_gelu_kernel<<<4096, 256, 0, stream>>>(f1, dw_w, dw_b, f2);
  gemm_kernel<<<dim3(64, 1), 256, 0, stream>>>(ffn2_w, f2, ffn2_b, x1, out, 256);
}

// Round 2
// 283.186 us; speedup vs baseline: 1.4198x; 1.4198x over previous
//
#include <hip/hip_runtime.h>
#include <math.h>

// B=1, C=64, H=W=64, N=4096, heads=8, dh=8, inner=64, hid_lc=32, hid_f=256.
#define NPIX 4096
#define IMG 64

// ---------------------------------------------------------------------------
// lc1 + luma pooling fused:
//   h1[32][4096] = relu(conv3x3(luma, lc1_w)+b)   (1 in-ch, pad=1)
//   pooled[p] = avgpool3x3(1-luma) (count_include_pad -> /9)
//   sum[0] += block partial sums (atomic; pre-zeroed by memset)
__global__ __launch_bounds__(256) void lc1_kernel(
    const float* __restrict__ luma, const float* __restrict__ w,
    const float* __restrict__ b, float* __restrict__ h1,
    float* __restrict__ pooled, float* __restrict__ sum) {
  __shared__ float red[256];
  int tid = threadIdx.x;
  int p = blockIdx.x * 256 + tid;
  int py = p >> 6, px = p & 63;
  float v[9];
#pragma unroll
  for (int dy = 0; dy < 3; dy++)
#pragma unroll
    for (int dx = 0; dx < 3; dx++) {
      int y = py + dy - 1, x = px + dx - 1;
      v[dy * 3 + dx] =
          (y >= 0 && y < IMG && x >= 0 && x < IMG) ? luma[y * IMG + x] : 0.f;
    }
  for (int oc = 0; oc < 32; oc++) {
    float s = b[oc];
#pragma unroll
    for (int t = 0; t < 9; t++) s = fmaf(w[oc * 9 + t], v[t], s);
    h1[oc * NPIX + p] = fmaxf(s, 0.f);
  }
  // pooled (1-luma) with zero pad: sum(1-l) over in-bounds = cnt - sum(l)
  float sv = 0.f;
#pragma unroll
  for (int t = 0; t < 9; t++) sv += v[t];
  float cy = 3.f - (py == 0 ? 1.f : 0.f) - (py == 63 ? 1.f : 0.f);
  float cx = 3.f - (px == 0 ? 1.f : 0.f) - (px == 63 ? 1.f : 0.f);
  float pv = (cy * cx - sv) * (1.f / 9.f);
  pooled[p] = pv;
  red[tid] = pv;
  __syncthreads();
  for (int st = 128; st > 0; st >>= 1) {
    if (tid < st) red[tid] += red[tid + st];
    __syncthreads();
  }
  if (tid == 0) atomicAdd(sum, red[0]);
}

// ---------------------------------------------------------------------------
// lc2: h2[32][4096] = relu(conv3x3(h1, lc2_w[32][32][3][3]) + b), pad=1.
__global__ __launch_bounds__(256) void lc2_kernel(
    const float* __restrict__ h1, const float* __restrict__ w,
    const float* __restrict__ b, float* __restrict__ h2) {
  __shared__ float tin[32][324];  // 18x18 halo per ic
  __shared__ float sw[4][32][9];
  int tile = blockIdx.x, ocg = blockIdx.y;
  int ty0 = (tile >> 2) * 16, tx0 = (tile & 3) * 16;
  for (int idx = threadIdx.x; idx < 32 * 324; idx += 256) {
    int ic = idx / 324, pos = idx % 324;
    int py = pos / 18, px = pos % 18;
    int gy = ty0 + py - 1, gx = tx0 + px - 1;
    tin[ic][pos] = (gy >= 0 && gy < IMG && gx >= 0 && gx < IMG)
                       ? h1[ic * NPIX + gy * IMG + gx]
                       : 0.f;
  }
  for (int idx = threadIdx.x; idx < 4 * 32 * 9; idx += 256) {
    int o = idx / 288, r = idx % 288;
    sw[o][r / 9][r % 9] = w[(ocg * 4 + o) * 288 + r];
  }
  __syncthreads();
  int ly = threadIdx.x >> 4, lx = threadIdx.x & 15;
  int p = (ty0 + ly) * IMG + tx0 + lx;
  float acc[4];
#pragma unroll
  for (int o = 0; o < 4; o++) acc[o] = b[ocg * 4 + o];
  for (int ic = 0; ic < 32; ic++) {
    float v[9];
#pragma unroll
    for (int dy = 0; dy < 3; dy++)
#pragma unroll
      for (int dx = 0; dx < 3; dx++)
        v[dy * 3 + dx] = tin[ic][(ly + dy) * 18 + lx + dx];
#pragma unroll
    for (int o = 0; o < 4; o++)
#pragma unroll
      for (int t = 0; t < 9; t++) acc[o] = fmaf(sw[o][ic][t], v[t], acc[o]);
  }
#pragma unroll
  for (int o = 0; o < 4; o++)
    h2[(ocg * 4 + o) * NPIX + p] = fmaxf(acc[o], 0.f);
}

// ---------------------------------------------------------------------------
// Fused per-pixel LayerNorm (over 64 ch) + 1x1 conv GEMM:
//   C[m0+0..63][n0+0..63] = W[m][:] . LN(X)[:, n] + bias[m]
// grid (64 n-blocks, M/64); block 256; 4x4 outputs/thread.
__global__ __launch_bounds__(256) void ln_gemm_kernel(
    const float* __restrict__ X, const float* __restrict__ lnw,
    const float* __restrict__ lnb, const float* __restrict__ W,
    const float* __restrict__ bias, float* __restrict__ C) {
  __shared__ float xs[64][64];
  __shared__ float wsh[64][64];  // [k][m]
  __shared__ float psum[4][64];
  __shared__ float mu[64];
  __shared__ float rs[64];
  int n0 = blockIdx.x * 64, m0 = blockIdx.y * 64;
  int tid = threadIdx.x;
  int c = tid >> 2, pg = (tid & 3) * 16;
  {
    const float4* src = (const float4*)&X[c * NPIX + n0 + pg];
    float4* dst = (float4*)&xs[c][pg];
    dst[0] = src[0]; dst[1] = src[1]; dst[2] = src[2]; dst[3] = src[3];
  }
  {
    int m = tid >> 2, kg = (tid & 3) * 16;
    const float4* wr = (const float4*)&W[(m0 + m) * 64 + kg];
    float4 w0 = wr[0], w1 = wr[1], w2 = wr[2], w3 = wr[3];
    float wv[16] = {w0.x, w0.y, w0.z, w0.w, w1.x, w1.y, w1.z, w1.w,
                    w2.x, w2.y, w2.z, w2.w, w3.x, w3.y, w3.z, w3.w};
#pragma unroll
    for (int j = 0; j < 16; j++) wsh[kg + j][m] = wv[j];
  }
  __syncthreads();
  int px = tid & 63, qq = tid >> 6;
  float s = 0.f;
#pragma unroll
  for (int cc = 0; cc < 16; cc++) s += xs[qq * 16 + cc][px];
  psum[qq][px] = s;
  __syncthreads();
  if (tid < 64) {
    float t = psum[0][tid] + psum[1][tid] + psum[2][tid] + psum[3][tid];
    mu[tid] = t * (1.f / 64.f);
  }
  __syncthreads();
  float mm = mu[px];
  s = 0.f;
#pragma unroll
  for (int cc = 0; cc < 16; cc++) {
    float d = xs[qq * 16 + cc][px] - mm;
    s = fmaf(d, d, s);
  }
  psum[qq][px] = s;
  __syncthreads();
  if (tid < 64) {
    float t = psum[0][tid] + psum[1][tid] + psum[2][tid] + psum[3][tid];
    rs[tid] = rsqrtf(t * (1.f / 64.f) + 1e-5f);
  }
  __syncthreads();
  {
    float wc = lnw[c], bc = lnb[c];
#pragma unroll
    for (int j = 0; j < 16; j++) {
      int p = pg + j;
      xs[c][p] = (xs[c][p] - mu[p]) * rs[p] * wc + bc;
    }
  }
  __syncthreads();
  int tx = tid & 15, ty = tid >> 4;
  float acc[4][4] = {};
#pragma unroll 8
  for (int kk = 0; kk < 64; kk++) {
    float4 a = *(const float4*)&wsh[kk][ty * 4];
    float4 b4 = *(const float4*)&xs[kk][tx * 4];
    float av[4] = {a.x, a.y, a.z, a.w};
    float bv[4] = {b4.x, b4.y, b4.z, b4.w};
#pragma unroll
    for (int im = 0; im < 4; im++)
#pragma unroll
      for (int in = 0; in < 4; in++)
        acc[im][in] = fmaf(av[im], bv[in], acc[im][in]);
  }
#pragma unroll
  for (int im = 0; im < 4; im++) {
    int m = m0 + ty * 4 + im;
    float bv = bias[m];
    float4 o = make_float4(acc[im][0] + bv, acc[im][1] + bv, acc[im][2] + bv,
                           acc[im][3] + bv);
    *(float4*)&C[m * NPIX + n0 + tx * 4] = o;
  }
}

// ---------------------------------------------------------------------------
// Thin GEMM: C[M][4096] = W[M][K] * X[K][4096] + bias (+resid)
// tile 16m x 64n; grid (64, M/16); block 256; 4 outputs/thread.
__global__ __launch_bounds__(256) void gemm16_kernel(
    const float* __restrict__ W, const float* __restrict__ X,
    const float* __restrict__ bias, const float* __restrict__ resid,
    float* __restrict__ C, int K) {
  __shared__ float xs[32][64];
  __shared__ float wsh[32][16];  // [k][m]
  int n0 = blockIdx.x * 64, m0 = blockIdx.y * 16;
  int tid = threadIdx.x;
  int m = tid >> 4, ng = tid & 15;
  float acc[4] = {};
  for (int k0 = 0; k0 < K; k0 += 32) {
    {
      int i0 = tid * 2;  // float4 index into 32x64 tile
      int k = i0 >> 4, nf = (i0 & 15) * 4;
      *(float4*)&xs[k][nf] = *(const float4*)&X[(k0 + k) * NPIX + n0 + nf];
      int i1 = i0 + 1;
      int k1 = i1 >> 4, nf1 = (i1 & 15) * 4;
      *(float4*)&xs[k1][nf1] = *(const float4*)&X[(k0 + k1) * NPIX + n0 + nf1];
    }
#pragma unroll
    for (int e = tid; e < 512; e += 256) {
      int mm = e >> 5, kk = e & 31;
      wsh[kk][mm] = W[(m0 + mm) * K + k0 + kk];
    }
    __syncthreads();
#pragma unroll 8
    for (int kk = 0; kk < 32; kk++) {
      float a = wsh[kk][m];
      float4 b4 = *(const float4*)&xs[kk][ng * 4];
      acc[0] = fmaf(a, b4.x, acc[0]);
      acc[1] = fmaf(a, b4.y, acc[1]);
      acc[2] = fmaf(a, b4.z, acc[2]);
      acc[3] = fmaf(a, b4.w, acc[3]);
    }
    __syncthreads();
  }
  int row = m0 + m;
  float bv = bias[row];
  float4 o = make_float4(acc[0] + bv, acc[1] + bv, acc[2] + bv, acc[3] + bv);
  if (resid) {
    const float4 r4 = *(const float4*)&resid[row * NPIX + n0 + ng * 4];
    o.x += r4.x; o.y += r4.y; o.z += r4.z; o.w += r4.w;
  }
  *(float4*)&C[row * NPIX + n0 + ng * 4] = o;
}

// ---------------------------------------------------------------------------
// Modulate qkv with (g, bt); q += alpha*(pooled - mean); pre-scale q by
// dh^-0.5 * log2(e) (softmax done in exp2 domain); repack to [h][n][d].
__global__ __launch_bounds__(256) void qkvmod_kernel(
    const float* __restrict__ qkv, const float* __restrict__ g,
    const float* __restrict__ bt, const float* __restrict__ pooled,
    const float* __restrict__ sum, const float* __restrict__ alpha,
    float* __restrict__ q, float* __restrict__ k, float* __restrict__ v) {
  const float QSCALE = 0.35355339059327376f * 1.4426950408889634f;
  int t = blockIdx.x * 256 + threadIdx.x;  // h*4096+n
  int n = t & 4095, h = t >> 12;
  float mean = sum[0] * (1.f / 4096.f);
  float iv = alpha[0] * (pooled[n] - mean);
  float* dsts[3] = {q, k, v};
#pragma unroll
  for (int part = 0; part < 3; part++) {
    float out[8];
#pragma unroll
    for (int d = 0; d < 8; d++) {
      int c = h * 8 + d;
      float r = fmaf(g[c * NPIX + n], qkv[(part * 64 + c) * NPIX + n],
                     bt[c * NPIX + n]);
      if (part == 0) r = (r + iv) * QSCALE;
      out[d] = r;
    }
    float4* dp = (float4*)&dsts[part][(size_t)(h * NPIX + n) * 8];
    dp[0] = make_float4(out[0], out[1], out[2], out[3]);
    dp[1] = make_float4(out[4], out[5], out[6], out[7]);
  }
}

// ---------------------------------------------------------------------------
// Flash-decode attention partials, exp2 domain, R=4 rows/thread, chunk C=4.
// grid (4 iblocks, 8 heads, JP jparts); block 256. slice = 4096/JP.
__global__ __launch_bounds__(256, 2) void attn_kernel(
    const float* __restrict__ q, const float* __restrict__ k,
    const float* __restrict__ v, float* __restrict__ pacc,
    float* __restrict__ pml, int slice) {
  __shared__ float ks[256][8];
  __shared__ float vs[256][8];
  int tid = threadIdx.x;
  int h = blockIdx.y, jp = blockIdx.z;
  int i0 = blockIdx.x * 1024 + tid;
  float qr[4][8], m[4], l[4], acc[4][8];
#pragma unroll
  for (int r = 0; r < 4; r++) {
    const float4* qp = (const float4*)(q + (size_t)(h * NPIX + i0 + r * 256) * 8);
    float4 q0 = qp[0], q1 = qp[1];
    qr[r][0] = q0.x; qr[r][1] = q0.y; qr[r][2] = q0.z; qr[r][3] = q0.w;
    qr[r][4] = q1.x; qr[r][5] = q1.y; qr[r][6] = q1.z; qr[r][7] = q1.w;
    m[r] = -INFINITY;
    l[r] = 0.f;
#pragma unroll
    for (int d = 0; d < 8; d++) acc[r][d] = 0.f;
  }
  int jbase = jp * slice;
  for (int jt = 0; jt < slice; jt += 256) {
    const float4* kg = (const float4*)(k + (size_t)(h * NPIX + jbase + jt) * 8);
    const float4* vg = (const float4*)(v + (size_t)(h * NPIX + jbase + jt) * 8);
    float4* ksv = (float4*)ks;
    float4* vsv = (float4*)vs;
#pragma unroll
    for (int idx = tid; idx < 512; idx += 256) {
      ksv[idx] = kg[idx];
      vsv[idx] = vg[idx];
    }
    __syncthreads();
    for (int jc = 0; jc < 256; jc += 4) {
      float s[4][4];
#pragma unroll
      for (int jj = 0; jj < 4; jj++) {
        float4 k0 = *(const float4*)&ks[jc + jj][0];
        float4 k1 = *(const float4*)&ks[jc + jj][4];
#pragma unroll
        for (int r = 0; r < 4; r++) {
          float t = qr[r][0] * k0.x;
          t = fmaf(qr[r][1], k0.y, t);
          t = fmaf(qr[r][2], k0.z, t);
          t = fmaf(qr[r][3], k0.w, t);
          t = fmaf(qr[r][4], k1.x, t);
          t = fmaf(qr[r][5], k1.y, t);
          t = fmaf(qr[r][6], k1.z, t);
          t = fmaf(qr[r][7], k1.w, t);
          s[r][jj] = t;
        }
      }
#pragma unroll
      for (int r = 0; r < 4; r++) {
        float cm = fmaxf(fmaxf(s[r][0], s[r][1]), fmaxf(s[r][2], s[r][3]));
        float mn = fmaxf(m[r], cm);
        float corr = __builtin_amdgcn_exp2f(m[r] - mn);
        m[r] = mn;
        l[r] *= corr;
#pragma unroll
        for (int d = 0; d < 8; d++) acc[r][d] *= corr;
      }
#pragma unroll
      for (int jj = 0; jj < 4; jj++) {
        float4 v0 = *(const float4*)&vs[jc + jj][0];
        float4 v1 = *(const float4*)&vs[jc + jj][4];
#pragma unroll
        for (int r = 0; r < 4; r++) {
          float p = __builtin_amdgcn_exp2f(s[r][jj] - m[r]);
          l[r] += p;
          acc[r][0] = fmaf(p, v0.x, acc[r][0]);
          acc[r][1] = fmaf(p, v0.y, acc[r][1]);
          acc[r][2] = fmaf(p, v0.z, acc[r][2]);
          acc[r][3] = fmaf(p, v0.w, acc[r][3]);
          acc[r][4] = fmaf(p, v1.x, acc[r][4]);
          acc[r][5] = fmaf(p, v1.y, acc[r][5]);
          acc[r][6] = fmaf(p, v1.z, acc[r][6]);
          acc[r][7] = fmaf(p, v1.w, acc[r][7]);
        }
      }
    }
    __syncthreads();
  }
#pragma unroll
  for (int r = 0; r < 4; r++) {
    size_t base = (size_t)((jp * 8 + h) * NPIX + i0 + r * 256);
    float4* pa = (float4*)&pacc[base * 8];
    pa[0] = make_float4(acc[r][0], acc[r][1], acc[r][2], acc[r][3]);
    pa[1] = make_float4(acc[r][4], acc[r][5], acc[r][6], acc[r][7]);
    pml[base * 2] = m[r];
    pml[base * 2 + 1] = l[r];
  }
}

// Combine JP j-partitions (exp2 domain); write attno[c=h*8+d][n].
__global__ __launch_bounds__(256) void attn_combine_kernel(
    const float* __restrict__ pacc, const float* __restrict__ pml,
    float* __restrict__ attno, int JP) {
  int t = blockIdx.x * 256 + threadIdx.x;  // h*4096+n
  int n = t & 4095, h = t >> 12;
  float M = -INFINITY;
  for (int p = 0; p < JP; p++)
    M = fmaxf(M, pml[(size_t)((p * 8 + h) * NPIX + n) * 2]);
  float L = 0.f, o[8] = {};
  for (int p = 0; p < JP; p++) {
    size_t base = (size_t)((p * 8 + h) * NPIX + n);
    float mm = pml[base * 2], ll = pml[base * 2 + 1];
    float c = __builtin_amdgcn_exp2f(mm - M);
    L = fmaf(ll, c, L);
#pragma unroll
    for (int d = 0; d < 8; d++) o[d] = fmaf(pacc[base * 8 + d], c, o[d]);
  }
  float inv = 1.f / L;
#pragma unroll
  for (int d = 0; d < 8; d++) attno[(h * 8 + d) * NPIX + n] = o[d] * inv;
}

// ---------------------------------------------------------------------------
// Depthwise 3x3 (pad=1, groups=256) + exact GELU; 4 horizontal px/thread.
__global__ __launch_bounds__(256) void dw_gelu_kernel(
    const float* __restrict__ f1, const float* __restrict__ w,
    const float* __restrict__ b, float* __restrict__ f2) {
  int t = blockIdx.x * 256 + threadIdx.x;  // 0..262143
  int c = t >> 10, pq = t & 1023;
  int py = pq >> 4, px0 = (pq & 15) << 2;
  const float* base = f1 + c * NPIX;
  float wv[9];
#pragma unroll
  for (int i = 0; i < 9; i++) wv[i] = w[c * 9 + i];
  float bc = b[c];
  float a[4] = {bc, bc, bc, bc};
#pragma unroll
  for (int dy = 0; dy < 3; dy++) {
    int y = py + dy - 1;
    if (y < 0 || y > 63) continue;
    const float* row = base + y * IMG + px0;
    float4 mid = *(const float4*)row;
    float left = (px0 > 0) ? row[-1] : 0.f;
    float right = (px0 < 60) ? row[4] : 0.f;
    float win[6] = {left, mid.x, mid.y, mid.z, mid.w, right};
#pragma unroll
    for (int o = 0; o < 4; o++)
#pragma unroll
      for (int dx = 0; dx < 3; dx++)
        a[o] = fmaf(wv[dy * 3 + dx], win[o + dx], a[o]);
  }
  float4 o4;
  float* op = &o4.x;
#pragma unroll
  for (int o = 0; o < 4; o++)
    op[o] = 0.5f * a[o] * (1.f + erff(a[o] * 0.70710678118654752f));
  *(float4*)&f2[c * NPIX + py * IMG + px0] = o4;
}

// ---------------------------------------------------------------------------
extern "C" void kernel_launch(void* const* d_in, const int* in_sizes, int n_in,
                              void* d_out, int out_size, void* d_ws,
                              size_t ws_size, hipStream_t stream) {
  const float* x      = (const float*)d_in[0];
  const float* luma   = (const float*)d_in[1];
  const float* ln1_w  = (const float*)d_in[2];
  const float* ln1_b  = (const float*)d_in[3];
  const float* qkv_w  = (const float*)d_in[4];
  const float* qkv_b  = (const float*)d_in[5];
  const float* proj_w = (const float*)d_in[6];
  const float* proj_b = (const float*)d_in[7];
  const float* lc1_w  = (const float*)d_in[8];
  const float* lc1_b  = (const float*)d_in[9];
  const float* lc2_w  = (const float*)d_in[10];
  const float* lc2_b  = (const float*)d_in[11];
  const float* gam_w  = (const float*)d_in[12];
  const float* gam_b  = (const float*)d_in[13];
  const float* bet_w  = (const float*)d_in[14];
  const float* bet_b  = (const float*)d_in[15];
  const float* alpha  = (const float*)d_in[16];
  const float* ln2_w  = (const float*)d_in[17];
  const float* ln2_b  = (const float*)d_in[18];
  const float* ffn1_w = (const float*)d_in[19];
  const float* ffn1_b = (const float*)d_in[20];
  const float* dw_w   = (const float*)d_in[21];
  const float* dw_b   = (const float*)d_in[22];
  const float* ffn2_w = (const float*)d_in[23];
  const float* ffn2_b = (const float*)d_in[24];
  float* out = (float*)d_out;

  float* w = (float*)d_ws;
  // Persistent buffers
  float* pooled = w + 0;        // 4096
  float* sum    = w + 4096;     // 64 (use [0])
  float* qb     = w + 4160;     // 262144
  float* kb     = w + 266304;   // 262144
  float* vb     = w + 528448;   // 262144
  float* attno  = w + 790592;   // 262144
  float* x1     = w + 1052736;  // 262144
  float* f1     = w + 1314880;  // 1048576
  float* f2     = w + 2363456;  // 1048576
  // Scratch region (pre-attn buffers alias attention partials)
  float* S      = w + 3412032;
  float* h1  = S + 0;       // 131072
  float* h2  = S + 131072;  // 131072
  float* g   = S + 262144;  // 262144
  float* bt  = S + 524288;  // 262144
  float* qkv = S + 786432;  // 786432  (pre-attn total 1572864)
  // Partials: JP*262144 (pacc) + JP*65536 (pml)
  size_t wfloats = ws_size / 4;
  int JP = (wfloats >= 3412032 + 16 * 327680) ? 16
         : (wfloats >= 3412032 + 8 * 327680) ? 8 : 4;
  float* pacc = S;
  float* pml  = S + (size_t)JP * 262144;
  int slice = NPIX / JP;

  hipMemsetAsync(sum, 0, sizeof(float), stream);
  // luma conditioning branch
  lc1_kernel<<<16, 256, 0, stream>>>(luma, lc1_w, lc1_b, h1, pooled, sum);
  lc2_kernel<<<dim3(16, 8), 256, 0, stream>>>(h1, lc2_w, lc2_b, h2);
  gemm16_kernel<<<dim3(64, 4), 256, 0, stream>>>(gam_w, h2, gam_b, nullptr, g, 32);
  gemm16_kernel<<<dim3(64, 4), 256, 0, stream>>>(bet_w, h2, bet_b, nullptr, bt, 32);
  // attention branch
  ln_gemm_kernel<<<dim3(64, 3), 256, 0, stream>>>(x, ln1_w, ln1_b, qkv_w, qkv_b, qkv);
  qkvmod_kernel<<<128, 256, 0, stream>>>(qkv, g, bt, pooled, sum, alpha, qb, kb, vb);
  attn_kernel<<<dim3(4, 8, JP), 256, 0, stream>>>(qb, kb, vb, pacc, pml, slice);
  attn_combine_kernel<<<128, 256, 0, stream>>>(pacc, pml, attno, JP);
  gemm16_kernel<<<dim3(64, 4), 256, 0, stream>>>(proj_w, attno, proj_b, x, x1, 64);
  // FFN branch
  ln_gemm_kernel<<<dim3(64, 4), 256, 0, stream>>>(x1, ln2_w, ln2_b, ffn1_w, ffn1_b, f1);
  dw_gelu_kernel<<<1024, 256, 0, stream>>>(f1, dw_w, dw_b, f2);
  gemm16_kernel<<<dim3(64, 4), 256, 0, stream>>>(ffn2_w, f2, ffn2_b, x1, out, 256);
}